// Round 4
// baseline (432.141 us; speedup 1.0000x reference)
//
#include <hip/hip_runtime.h>
#include <hip/hip_bf16.h>

#define NB   64
#define NC   1024
#define NQ   128
#define DIMD 512
#define BK   64
#define NKC  (DIMD / BK)   // 8 K-chunks
#define TM   128           // rows per context tile
#define NTILE (NC / TM)    // 8 tiles

using short8  = __attribute__((ext_vector_type(8))) short;
using f32x4   = __attribute__((ext_vector_type(4))) float;
typedef __fp16 half2v __attribute__((ext_vector_type(2)));

__device__ inline float dot4(float4 a, float4 b) {
    return a.x * b.x + a.y * b.y + a.z * b.z + a.w * b.w;
}
__device__ inline float bf2f(unsigned short u) {
    unsigned x = ((unsigned)u) << 16;
    return __builtin_bit_cast(float, x);
}
__device__ inline ushort2 pkbf(float a, float b) {
    union { __hip_bfloat162 h; ushort2 u; } x;
    x.h = __float22bfloat162_rn(make_float2(a, b));
    return x.u;
}
// global -> LDS direct 16B copy (wave-uniform LDS base + lane*16)
#define GLOAD_LDS16(g, l)                                             \
    __builtin_amdgcn_global_load_lds(                                 \
        (const __attribute__((address_space(1))) void*)(g),           \
        (__attribute__((address_space(3))) void*)(l), 16, 0, 0)

// ---------------------------------------------------------------------------
// P1: one wave per row (ctx rows then qry rows).
//   ctx row: C2 = bf16(c), cwG = c . wc
//   qry row: Q2 = bf16(wm * q), qwG = q . wq
// Grid 18432 x 256 (73728 waves).
// ---------------------------------------------------------------------------
__global__ __launch_bounds__(256) void prep_kernel(
    const float* __restrict__ ctx, const float* __restrict__ qry,
    const float* __restrict__ w0,
    unsigned short* __restrict__ C2, unsigned short* __restrict__ Q2,
    float* __restrict__ cwG, float* __restrict__ qwG)
{
    const int wv   = blockIdx.x * 4 + (threadIdx.x >> 6);
    const int lane = threadIdx.x & 63;
    const int c0 = lane * 4, c1 = 256 + lane * 4;

    if (wv < NB * NC) {  // context row
        const float* src = ctx + (size_t)wv * DIMD;
        float4 v0 = *(const float4*)(src + c0);
        float4 v1 = *(const float4*)(src + c1);
        float4 w0v = *(const float4*)(w0 + c0);
        float4 w1v = *(const float4*)(w0 + c1);
        float d = dot4(v0, w0v) + dot4(v1, w1v);
#pragma unroll
        for (int off = 1; off < 64; off <<= 1) d += __shfl_xor(d, off);
        if (lane == 0) cwG[wv] = d;
        ushort2 p0 = pkbf(v0.x, v0.y), p1 = pkbf(v0.z, v0.w);
        ushort2 p2 = pkbf(v1.x, v1.y), p3 = pkbf(v1.z, v1.w);
        union { ushort2 u2[2]; uint2 u; } a, bb;
        a.u2[0] = p0; a.u2[1] = p1; bb.u2[0] = p2; bb.u2[1] = p3;
        *(uint2*)&C2[(size_t)wv * DIMD + c0] = a.u;
        *(uint2*)&C2[(size_t)wv * DIMD + c1] = bb.u;
    } else {             // query row
        const int r2 = wv - NB * NC;
        const float* src = qry + (size_t)r2 * DIMD;
        float4 v0 = *(const float4*)(src + c0);
        float4 v1 = *(const float4*)(src + c1);
        float4 wq0 = *(const float4*)(w0 + DIMD + c0);
        float4 wq1 = *(const float4*)(w0 + DIMD + c1);
        float4 wm0 = *(const float4*)(w0 + 2 * DIMD + c0);
        float4 wm1 = *(const float4*)(w0 + 2 * DIMD + c1);
        float d = dot4(v0, wq0) + dot4(v1, wq1);
#pragma unroll
        for (int off = 1; off < 64; off <<= 1) d += __shfl_xor(d, off);
        if (lane == 0) qwG[r2] = d;
        ushort2 p0 = pkbf(v0.x * wm0.x, v0.y * wm0.y), p1 = pkbf(v0.z * wm0.z, v0.w * wm0.w);
        ushort2 p2 = pkbf(v1.x * wm1.x, v1.y * wm1.y), p3 = pkbf(v1.z * wm1.z, v1.w * wm1.w);
        union { ushort2 u2[2]; uint2 u; } a, bb;
        a.u2[0] = p0; a.u2[1] = p1; bb.u2[0] = p2; bb.u2[1] = p3;
        *(uint2*)&Q2[(size_t)r2 * DIMD + c0] = a.u;
        *(uint2*)&Q2[(size_t)r2 * DIMD + c1] = bb.u;
    }
}

// ---------------------------------------------------------------------------
// GEMM: A from C2 via swizzled global_load_lds, B direct from Q2 (L2-hot).
// Grid (NB, NTILE), 256 threads, 2x2 wave grid over 128x128.
// LDS A layout: short index = r*64 + ((kg ^ (r&7))*8 + (k&7)), kg = k>>3.
// ---------------------------------------------------------------------------
__global__ __launch_bounds__(256) void gemm_stats(
    const unsigned short* __restrict__ C2, const unsigned short* __restrict__ Q2,
    const float* __restrict__ cwG, const float* __restrict__ qwG,
    float* __restrict__ stats, unsigned short* __restrict__ simh)
{
    __shared__ __attribute__((aligned(16))) unsigned short As[TM * BK];
    __shared__ float cwL[TM], qwL[NQ], sL[2][NQ];

    const int tid  = threadIdx.x;
    const int b    = blockIdx.x;
    const int bt   = blockIdx.y;
    const int i0   = bt * TM;
    const int w    = tid >> 6;
    const int lane = tid & 63;
    const int wr   = w >> 1, wcg = w & 1;
    const int RB   = wr * 64, CB = wcg * 64;
    const int n16  = lane & 15, qd = lane >> 4;

    if (tid < TM) cwL[tid] = cwG[b * NC + i0 + tid];
    if (tid < NQ) qwL[tid] = qwG[b * NQ + tid];

    f32x4 acc[4][4];
#pragma unroll
    for (int ri = 0; ri < 4; ri++)
#pragma unroll
        for (int ci = 0; ci < 4; ci++)
#pragma unroll
            for (int e = 0; e < 4; e++) acc[ri][ci][e] = 0.f;

    // staging address precompute: lane -> (row a=lane>>3, slot p=lane&7)
    const int a8 = lane >> 3, p8 = lane & 7;
    const int kgd = p8 ^ (a8 & 7);                         // logical k-group fetched
    const unsigned short* gA = C2 + ((size_t)(b * NC + i0 + w * 32 + a8)) * DIMD + kgd * 8;
    unsigned short* ldsA = &As[(w * 32) * BK];
    const int sw = n16 & 7;                                // ds_read swizzle key

    for (int kc = 0; kc < NKC; kc++) {
        const int k0 = kc * BK;
        __syncthreads();   // prior MFMA done reading As (covers cwL/qwL on kc=0)
#pragma unroll
        for (int u = 0; u < 4; u++)
            GLOAD_LDS16(gA + k0 + (size_t)u * 8 * DIMD, ldsA + u * 8 * BK);
        __syncthreads();
#pragma unroll
        for (int ks = 0; ks < 2; ks++) {
            short8 af[4], bfr[4];
#pragma unroll
            for (int ci = 0; ci < 4; ci++)
                bfr[ci] = *(const short8*)(Q2 + ((size_t)(b * NQ + CB + ci * 16 + n16)) * DIMD
                                           + k0 + ks * 32 + qd * 8);
#pragma unroll
            for (int ri = 0; ri < 4; ri++)
                af[ri] = *(const short8*)&As[(RB + ri * 16 + n16) * BK
                                             + (((ks * 4 + qd) ^ sw) * 8)];
#pragma unroll
            for (int ri = 0; ri < 4; ri++)
#pragma unroll
                for (int ci = 0; ci < 4; ci++)
                    acc[ri][ci] = __builtin_amdgcn_mfma_f32_16x16x32_bf16(
                        af[ri], bfr[ci], acc[ri][ci], 0, 0, 0);
        }
    }

    // Epilogue: v = acc + cw_i + qw_j; fp16 sim spill (col-major per tile) + col sum_exp.
    // C/D layout (16x16x32): col = lane&15, row = (lane>>4)*4 + reg
#pragma unroll
    for (int ci = 0; ci < 4; ci++) {
        const int col = CB + ci * 16 + n16;
        const float qwv = qwL[col];
        unsigned short* simCol = simh + ((size_t)(b * NTILE + bt) * NQ + col) * TM;
        float s = 0.f;
#pragma unroll
        for (int ri = 0; ri < 4; ri++) {
            const int rbase = RB + ri * 16 + qd * 4;
            float v0 = acc[ri][ci][0] + cwL[rbase + 0] + qwv;
            float v1 = acc[ri][ci][1] + cwL[rbase + 1] + qwv;
            float v2 = acc[ri][ci][2] + cwL[rbase + 2] + qwv;
            float v3 = acc[ri][ci][3] + cwL[rbase + 3] + qwv;
            s += __expf(v0) + __expf(v1) + __expf(v2) + __expf(v3);
            half2v h01 = __builtin_amdgcn_cvt_pkrtz(v0, v1);
            half2v h23 = __builtin_amdgcn_cvt_pkrtz(v2, v3);
            uint2 pk;
            pk.x = __builtin_bit_cast(unsigned, h01);
            pk.y = __builtin_bit_cast(unsigned, h23);
            *(uint2*)&simCol[rbase] = pk;
        }
        s += __shfl_xor(s, 16);
        s += __shfl_xor(s, 32);
        if (qd == 0) sL[wr][col] = s;
    }
    __syncthreads();
    if (tid < NQ)
        stats[(size_t)(b * NTILE + bt) * NQ + tid] = sL[0][tid] + sL[1][tid];
}

// K2b: Arow[b][d] = sum_j q[b][j][d] (fp32 exact). Grid (NB, 2), block 256.
__global__ void arow_kernel(const float* __restrict__ qry, float* __restrict__ arow)
{
    const int b = blockIdx.x, h = blockIdx.y;
    const int d = h * 256 + threadIdx.x;
    float a = 0.f;
    const float* base = qry + (size_t)b * NQ * DIMD + d;
    for (int j = 0; j < NQ; j++) a += base[(size_t)j * DIMD];
    arow[(size_t)b * DIMD + d] = a;
}

// K3: iz from stats (combine fused), r_i = sum_j exp(sim)*iz_j,
// Bpart[d] = sum_i r_i * bf16C[i][d]. Grid (NB, NTILE), block 256.
__global__ __launch_bounds__(256) void rb_kernel(
    const unsigned short* __restrict__ C2, const unsigned short* __restrict__ simh,
    const float* __restrict__ stats, float* __restrict__ bpart)
{
    __shared__ __attribute__((aligned(16))) unsigned short simL[NQ * TM];
    __shared__ float izL[NQ];
    __shared__ float rpart[2][TM];
    __shared__ float rfin[TM];

    const int tid = threadIdx.x;
    const int b = blockIdx.x, bt = blockIdx.y;
    const int i0 = bt * TM;

    if (tid < NQ) {
        float s = 0.f;
        for (int t = 0; t < NTILE; t++)
            s += stats[(size_t)(b * NTILE + t) * NQ + tid];
        izL[tid] = 1.0f / s;
    }
    const unsigned short* tileSrc = simh + (size_t)(b * NTILE + bt) * NQ * TM;
#pragma unroll
    for (int it = 0; it < 8; it++) {
        const int idx = (tid + it * 256) * 8;   // 16B per thread
        *(uint4*)&simL[idx] = *(const uint4*)&tileSrc[idx];
    }
    __syncthreads();

    const int i = tid & 127, jh = tid >> 7;
    float r = 0.f;
    for (int j2 = 0; j2 < 64; j2++) {
        const int j = jh * 64 + j2;
        __fp16 hv = __builtin_bit_cast(__fp16, simL[j * TM + i]);
        r += __expf((float)hv) * izL[j];
    }
    rpart[jh][i] = r;
    __syncthreads();
    if (tid < TM) rfin[tid] = rpart[0][tid] + rpart[1][tid];
    __syncthreads();

    const int d0 = tid * 2;
    float bx = 0.f, by = 0.f;
    const unsigned short* cb2 = C2 + ((size_t)(b * NC + i0)) * DIMD + d0;
    for (int ii = 0; ii < TM; ii++) {
        float rv = rfin[ii];
        ushort2 cv = *(const ushort2*)(cb2 + (size_t)ii * DIMD);
        bx += rv * bf2f(cv.x); by += rv * bf2f(cv.y);
    }
    float* bp = bpart + (size_t)(b * NTILE + bt) * DIMD + d0;
    bp[0] = bx; bp[1] = by;
}

// K4: reduce Brow partials + broadcast-write A and B. Grid (NB, 32), block 256.
__global__ void broadcast_out(const float* __restrict__ arow, const float* __restrict__ bpart,
                              float* __restrict__ out)
{
    const int b = blockIdx.x, ic = blockIdx.y;
    const int t = threadIdx.x;
    const int half = t >> 7;          // 0 -> A, 1 -> B (wave-uniform)
    const int l = t & 127;
    const int d0 = l * 4;
    float4 val;
    if (half == 0) {
        val = *(const float4*)&arow[(size_t)b * DIMD + d0];
    } else {
        val.x = val.y = val.z = val.w = 0.f;
        for (int t8 = 0; t8 < NTILE; t8++) {
            float4 v = *(const float4*)&bpart[(size_t)(b * NTILE + t8) * DIMD + d0];
            val.x += v.x; val.y += v.y; val.z += v.z; val.w += v.w;
        }
    }
    size_t base = (size_t)half * ((size_t)NB * NC * DIMD)
                + ((size_t)b * NC + (size_t)ic * 32) * DIMD + d0;
    for (int i = 0; i < 32; i++)
        *(float4*)&out[base + (size_t)i * DIMD] = val;
}

extern "C" void kernel_launch(void* const* d_in, const int* in_sizes, int n_in,
                              void* d_out, int out_size, void* d_ws, size_t ws_size,
                              hipStream_t stream)
{
    const float* ctx = (const float*)d_in[0];  // (64,1024,512) f32
    const float* qry = (const float*)d_in[1];  // (64,128,512) f32
    const float* w0  = (const float*)d_in[2];  // (1536,) f32
    float* out = (float*)d_out;
    char*  ws  = (char*)d_ws;

    float* stats = (float*)(ws);                         // 256 KB
    float* arow  = (float*)(ws + (1u << 20));            // 128 KB
    float* bpart = (float*)(ws + (2u << 20));            // 1 MB
    float* cwG   = (float*)(ws + (4u << 20));            // 256 KB
    float* qwG   = (float*)(ws + (5u << 20));            // 32 KB
    unsigned short* simh = (unsigned short*)(ws + (8u << 20));    // 16.8 MB
    unsigned short* C2   = (unsigned short*)(ws + (32u << 20));   // 67 MB
    unsigned short* Q2   = (unsigned short*)(ws + (104u << 20));  // 8.4 MB

    prep_kernel<<<18432, 256, 0, stream>>>(ctx, qry, w0, C2, Q2, cwG, qwG);
    arow_kernel<<<dim3(NB, 2), 256, 0, stream>>>(qry, arow);
    gemm_stats<<<dim3(NB, NTILE), 256, 0, stream>>>(C2, Q2, cwG, qwG, stats, simh);
    rb_kernel<<<dim3(NB, NTILE), 256, 0, stream>>>(C2, simh, stats, bpart);
    broadcast_out<<<dim3(NB, 32), 256, 0, stream>>>(arow, bpart, out);
}